// Round 5
// baseline (273.580 us; speedup 1.0000x reference)
//
#include <hip/hip_runtime.h>

// RoIAlign via TF crop_and_resize. Fixed problem shapes:
//   featuremap (N=2, C=256, H=200, W=304) fp32
//   rois       (M=2048, 5) fp32  [batch_id, x1, y1, x2, y2]
//   out        (M, C, 7, 7) fp32
//
// R2: XCD-pinned channel groups (fetch 382->194 MB).
// R4: per-thread scattered gathers (123 us) — TA-bound, 15% line util.
// R5: region staging BC=8 (139 us): right bytes but serial staging (VGPR=8).
// R6: v[5] register batch, BC=16 (143 us): 3.47 TB/s issue but 16-ch slab
//     thrashed the 4 MB XCD L2 (fetch 382 MB). Slab must stay <= 8 ch.
// R7: BB=2 x BC=8 + v[5] batch + single barrier (120 us, fetch 104 MB):
//     now VALU-issue bound — ~500 VALU insts/wave, over half of it
//     per-block-redundant geometry (12 fdiv chains, contract-off) recomputed
//     16x per box, sitting in front of the loads.
// R8: GEOMETRY PRE-KERNEL. geom_kernel (2048x14 lanes, ~5 us) computes the
//     bit-exact table math once per box -> 64-int record in d_ws
//     (yt[7],yb[7],xl[7],xr[7], ylerp[7],vy[7],xlerp[7],vx[7], ys,xs,imgbase).
//     Main kernel: zero divides, reads records (L2-hot, 16x reuse), keeps
//     R7's slab/batch/single-barrier structure.
//     (R8a: fix '#pragma clang fp' placement — must open a compound stmt.)
#define RA_C   256
#define RA_H   200
#define RA_W   304
#define RA_HW  (RA_H * RA_W)        // 60800
#define RA_CHW (RA_C * RA_HW)       // 15564800
#define CROPN  7
#define CROP2  (CROPN * CROPN)      // 49
#define OUT_M  (RA_C * CROP2)       // 12544 floats per box
#define BC     8                    // channels per block  (L2 slab constraint)
#define BB     2                    // boxes per block
#define REG_R  16                   // region rows   (proven bound)
#define REG_C  20                   // region cols   (5 float4, proven bound)
#define NF4    5                    // float4 per region row
#define CH_STR (REG_R * REG_C + 4)  // 324 floats: 16B-mult, +4 spreads banks
#define GREC   64                   // ints per box record in workspace

// ---------------- pre-kernel: per-box geometry tables ----------------
__global__ __launch_bounds__(256) void geom_kernel(
    const float* __restrict__ rois, const float* __restrict__ scale_p,
    int* __restrict__ ws, int M)
{
    const int gid = blockIdx.x * 256 + threadIdx.x;
    if (gid >= M * 2 * CROPN) return;
    // Replicate the reference's fp32 arithmetic exactly (no contraction)
    // so validity comparisons (y>=0, y<=H-1) match numpy bit-for-bit.
    {
        #pragma clang fp contract(off)
        const int m   = gid / (2 * CROPN);
        const int k14 = gid - m * (2 * CROPN);
        int* __restrict__ rec = ws + (size_t)m * GREC;
        const int axis = (k14 >= CROPN) ? 1 : 0;   // 0 = y, 1 = x
        const int k = axis ? (k14 - CROPN) : k14;
        const float scale = scale_p[0];
        const float* __restrict__ rr = rois + (size_t)m * 5;
        float lo, hi, szm1;
        if (axis == 0) { lo = rr[2] * scale; hi = rr[4] * scale; szm1 = (float)(RA_H - 1); }
        else           { lo = rr[1] * scale; hi = rr[3] * scale; szm1 = (float)(RA_W - 1); }
        float sp   = (hi - lo) / 7.0f;
        float n0   = (lo + sp * 0.5f - 0.5f) / szm1;
        float nsz  = sp * 6.0f / szm1;
        float b2   = n0 + nsz;
        float d    = (b2 - n0) * szm1 / 6.0f;
        float coord = n0 * szm1 + (float)k * d;
        float fl = floorf(coord);
        float ce = ceilf(coord);
        float lerp = coord - fl;
        int lo_i = (int)fminf(fmaxf(fl, 0.0f), szm1);
        int hi_i = (int)fminf(fmaxf(ce, 0.0f), szm1);
        float valid = (coord >= 0.0f && coord <= szm1) ? 1.0f : 0.0f;
        if (axis == 0) {
            rec[k]      = lo_i;
            rec[7 + k]  = hi_i;
            rec[28 + k] = __float_as_int(lerp);
            rec[35 + k] = __float_as_int(valid);
            if (k == 0) {
                rec[56] = lo_i;                          // ys == yt[0]
                rec[58] = (int)rr[0] * RA_CHW;           // imgbase
            }
        } else {
            rec[14 + k] = lo_i;
            rec[21 + k] = hi_i;
            rec[42 + k] = __float_as_int(lerp);
            rec[49 + k] = __float_as_int(valid);
            if (k == 0) rec[57] = lo_i & ~3;             // xs == xl[0] & ~3
        }
    }
}

// ---------------- main kernel ----------------
__global__ __launch_bounds__(256) void roialign_kernel(
    const float* __restrict__ fm, const int* __restrict__ ws,
    float* __restrict__ out)
{
    __shared__ __align__(16) float s_reg[BB * BC * CH_STR];   // 20736 B
    __shared__ int s_tab[BB][GREC];                           // 512 B

    const int t = threadIdx.x;

    // --- block -> (channel group, box pair) with XCD pinning ---
    const int bid   = blockIdx.x;
    const int numBG = gridDim.x >> 5;          // M / BB
    const int xcd   = bid & 7;
    const int r     = bid >> 3;                // [0, 4*numBG)
    const int cgl   = r / numBG;               // [0, 4)
    const int bg    = r - cgl * numBG;         // [0, numBG)
    const int m0    = bg * BB;
    const int c0    = (xcd * 4 + cgl) * BC;    // 8-ch slab: 3.9 MB/XCD < 4 MB L2

    const int bx = t >> 7;                     // my box within the pair
    const int* __restrict__ rec = ws + (size_t)(m0 + bx) * GREC;

    // region origin + image base (3 hot loads; records are L2-resident)
    const int ys   = rec[56];
    const int xs   = rec[57];
    const int base = rec[58] + c0 * RA_HW;     // < 2^31

    // --- issue 5 independent f4 loads (register batch) ---
    const int u   = t & 127;
    const int cc  = u >> 4;                    // 0..7: one channel / 16 lanes
    const int l16 = u & 15;
    const float* __restrict__ cp = fm + (size_t)(base + cc * RA_HW);
    float4 v[NF4];
    #pragma unroll
    for (int s = 0; s < NF4; ++s) {
        const int idx = l16 + (s << 4);        // 0..79: region f4 slot
        const int r2  = idx / 5;               // region row (magic mul)
        const int kk  = idx - r2 * 5;          // f4 within row
        const int row = min(ys + r2, RA_H - 1);        // clamp: dup rows, in-bounds
        const int col = min(xs + (kk << 2), RA_W - 4); // clamp: dup f4s, in-bounds
        v[s] = *reinterpret_cast<const float4*>(cp + row * RA_W + col);
        // clamped duplicate slots are provably never sampled.
    }

    // --- copy geometry records to LDS (coalesced, hidden under loads) ---
    if (t < BB * GREC) {
        const int b = t >> 6;                  // box
        const int w = t & 63;                  // word
        s_tab[b][w] = ws[(size_t)(m0 + b) * GREC + w];
    }

    // --- drain loads into LDS (5 contiguous b128 writes) ---
    {
        float* __restrict__ sp_ = s_reg + (bx * BC + cc) * CH_STR;
        #pragma unroll
        for (int s = 0; s < NF4; ++s) {
            const int idx = l16 + (s << 4);
            // float offset 4*idx == r2*REG_C + 4*kk  (REG_C==20, NF4==5)
            *reinterpret_cast<float4*>(sp_ + (idx << 2)) = v[s];
        }
    }
    __syncthreads();   // single barrier: covers tables + region

    // --- sampling: thread = (box bx, sample ij, 4-channel group) ---
    const int ij  = t & 63;                    // 49 active
    const int chg = (t >> 6) & 1;              // 0..1 -> channels 4*chg..+3
    if (ij < CROP2) {
        const int i = ij / CROPN;
        const int j = ij - i * CROPN;
        const int rT = min(s_tab[bx][i]      - ys, REG_R - 1);
        const int rB = min(s_tab[bx][7 + i]  - ys, REG_R - 1);
        const int cl = min(s_tab[bx][14 + j] - xs, REG_C - 1);
        const int cr = min(s_tab[bx][21 + j] - xs, REG_C - 1);
        const float yw = __int_as_float(s_tab[bx][28 + i]);
        const float vy = __int_as_float(s_tab[bx][35 + i]);
        const float xw = __int_as_float(s_tab[bx][42 + j]);
        const float vx = __int_as_float(s_tab[bx][49 + j]);
        const float vv = vy * vx;
        const int oT = rT * REG_C;
        const int oB = rB * REG_C;
        float* __restrict__ op =
            out + (size_t)(m0 + bx) * OUT_M + (size_t)(c0 + chg * 4) * CROP2 + ij;
        #pragma unroll
        for (int q = 0; q < 4; ++q) {
            const float* __restrict__ sp2 =
                s_reg + (bx * BC + chg * 4 + q) * CH_STR;
            const float tl = sp2[oT + cl];
            const float tr = sp2[oT + cr];
            const float bl = sp2[oB + cl];
            const float br = sp2[oB + cr];
            const float top = tl + (tr - tl) * xw;
            const float bot = bl + (br - bl) * xw;
            op[q * CROP2] = (top + (bot - top) * yw) * vv;
        }
    }
}

extern "C" void kernel_launch(void* const* d_in, const int* in_sizes, int n_in,
                              void* d_out, int out_size, void* d_ws, size_t ws_size,
                              hipStream_t stream) {
    const float* fm    = (const float*)d_in[0];
    const float* rois  = (const float*)d_in[1];
    const float* scale = (const float*)d_in[2];
    float* out = (float*)d_out;
    int* ws = (int*)d_ws;
    const int M = in_sizes[1] / 5;             // 2048
    const int numBG = M / BB;                  // 1024

    const int gthreads = M * 2 * CROPN;        // 28672
    geom_kernel<<<dim3((gthreads + 255) / 256), dim3(256), 0, stream>>>(
        rois, scale, ws, M);
    roialign_kernel<<<dim3(32 * numBG), dim3(256), 0, stream>>>(fm, ws, out);
}